// Round 1
// baseline (665.808 us; speedup 1.0000x reference)
//
#include <hip/hip_runtime.h>

#define NTOK 32768
#define CDIM 256

// ---------------------------------------------------------------------------
// Tiled fp32 GEMM: C[M,N] = A[M,K] * B[K,N], row-major. TM=TN=64, TK=16.
// Block = 256 threads (16x16), each thread computes a 4x4 micro-tile.
// Batch via blockIdx.z with element strides sA/sB/sC (sA=0 shares A).
// ---------------------------------------------------------------------------
__global__ __launch_bounds__(256) void gemm_tiled(
    const float* __restrict__ A, const float* __restrict__ B, float* __restrict__ C,
    int M, int N, int K, long sA, long sB, long sC)
{
    const int b = blockIdx.z;
    A += (long)b * sA; B += (long)b * sB; C += (long)b * sC;

    __shared__ float As[16][64];   // [k][m] transposed store
    __shared__ float Bs[16][64];   // [k][n]

    const int t  = threadIdx.x;
    const int tx = t & 15, ty = t >> 4;
    const int row0 = blockIdx.y * 64, col0 = blockIdx.x * 64;

    float acc[4][4] = {};

    for (int k0 = 0; k0 < K; k0 += 16) {
        // A tile: 64 rows x 16 k. thread t loads float4 along k: m=t/4, k=(t%4)*4
        {
            const int m = t >> 2, kk = (t & 3) << 2;
            const float4 av = *(const float4*)&A[(long)(row0 + m) * K + k0 + kk];
            As[kk + 0][m] = av.x; As[kk + 1][m] = av.y;
            As[kk + 2][m] = av.z; As[kk + 3][m] = av.w;
        }
        // B tile: 16 k x 64 n. thread t loads float4 along n: k=t/16, n=(t%16)*4
        {
            const int kb = t >> 4, n = (t & 15) << 2;
            *(float4*)&Bs[kb][n] = *(const float4*)&B[(long)(k0 + kb) * N + col0 + n];
        }
        __syncthreads();
        #pragma unroll
        for (int kk = 0; kk < 16; ++kk) {
            float a[4], bb[4];
            *(float4*)a  = *(const float4*)&As[kk][ty << 2];
            *(float4*)bb = *(const float4*)&Bs[kk][tx << 2];
            #pragma unroll
            for (int i = 0; i < 4; ++i)
                #pragma unroll
                for (int j = 0; j < 4; ++j)
                    acc[i][j] += a[i] * bb[j];
        }
        __syncthreads();
    }
    #pragma unroll
    for (int i = 0; i < 4; ++i)
        *(float4*)&C[(long)(row0 + (ty << 2) + i) * N + col0 + (tx << 2)] = *(float4*)&acc[i][0];
}

// ---------------------------------------------------------------------------
// Per-(batch, k-channel) max over n. One block per channel, 256 threads.
// ---------------------------------------------------------------------------
__global__ __launch_bounds__(256) void kmax_kernel(const float* __restrict__ qkv,
                                                   float* __restrict__ kmax)
{
    const int bc = blockIdx.x;            // b*256 + ch
    const int b = bc >> 8, ch = bc & 255;
    const float* row = qkv + ((long)b * 768 + 256 + ch) * NTOK;
    float m = -1e30f;
    for (int i = threadIdx.x; i < NTOK; i += 256) m = fmaxf(m, row[i]);
    #pragma unroll
    for (int off = 32; off > 0; off >>= 1) m = fmaxf(m, __shfl_down(m, off, 64));
    __shared__ float sm[4];
    if ((threadIdx.x & 63) == 0) sm[threadIdx.x >> 6] = m;
    __syncthreads();
    if (threadIdx.x == 0)
        kmax[bc] = fmaxf(fmaxf(sm[0], sm[1]), fmaxf(sm[2], sm[3]));
}

// ---------------------------------------------------------------------------
// context numerator num[b,h,d,e] = sum_n exp(k[n,d]-kmax[d]) * v[n,e]
// and denominator den[b, h*32+d] = sum_n exp(k[n,d]-kmax[d]).
// Grid (chunks, heads, b); block 256 threads; chunk of tokens staged in
// 128-token LDS tiles. Thread owns (d = t/8, e in {(t%8)*4 + 0..3}).
// Partial results combined with fp32 atomics (num/den zeroed beforehand).
// ---------------------------------------------------------------------------
#define CTILE 128
__global__ __launch_bounds__(256) void ctx_kernel(
    const float* __restrict__ qkv, const float* __restrict__ kmax,
    float* __restrict__ num, float* __restrict__ den, int tokens_per_block)
{
    const int chunk = blockIdx.x, h = blockIdx.y, b = blockIdx.z;
    const int n0 = chunk * tokens_per_block;
    const float* kbase = qkv + ((long)b * 768 + 256 + h * 32) * NTOK;
    const float* vbase = qkv + ((long)b * 768 + 512 + h * 32) * NTOK;

    __shared__ float ks[32][CTILE + 4];   // [d][tok], pad 4 to break bank stride
    __shared__ float vs[32][CTILE + 4];   // [e][tok]

    const int t = threadIdx.x;
    const int d = t >> 3, eg = t & 7;     // compute mapping
    const int lrow = t >> 3, lf = t & 7;  // load mapping (row, float4 group)
    const float km = kmax[b * 256 + h * 32 + lrow];

    float acc[4] = {0.f, 0.f, 0.f, 0.f};
    float dsum = 0.f;

    for (int tile = 0; tile < tokens_per_block; tile += CTILE) {
        #pragma unroll
        for (int j = 0; j < 4; ++j) {
            const int f = lf + 8 * j;     // float4 index 0..31 within row
            const long g = (long)lrow * NTOK + n0 + tile + f * 4;
            const float4 kv = *(const float4*)&kbase[g];
            const float4 vv = *(const float4*)&vbase[g];
            ks[lrow][f * 4 + 0] = __expf(kv.x - km);
            ks[lrow][f * 4 + 1] = __expf(kv.y - km);
            ks[lrow][f * 4 + 2] = __expf(kv.z - km);
            ks[lrow][f * 4 + 3] = __expf(kv.w - km);
            *(float4*)&vs[lrow][f * 4] = vv;
        }
        __syncthreads();
        for (int tok = 0; tok < CTILE; ++tok) {
            const float ek = ks[d][tok];
            dsum += ek;
            #pragma unroll
            for (int i = 0; i < 4; ++i) acc[i] += ek * vs[eg * 4 + i][tok];
        }
        __syncthreads();
    }
    float* nrow = num + (((long)(b * 8 + h) * 32 + d) * 32);
    #pragma unroll
    for (int i = 0; i < 4; ++i) atomicAdd(&nrow[eg * 4 + i], acc[i]);
    if (eg == 0) atomicAdd(&den[b * 256 + h * 32 + d], dsum);
}

// ---------------------------------------------------------------------------
// q softmax over Dh=32, in place on qkv rows 0..255. One thread per
// (b, h, token); channel reads are coalesced across threads (consecutive tok).
// ---------------------------------------------------------------------------
__global__ __launch_bounds__(256) void qsoft_kernel(float* __restrict__ qkv)
{
    const long tid = (long)blockIdx.x * 256 + threadIdx.x;  // over b*8*NTOK
    const int tok = (int)(tid & (NTOK - 1));
    const long rest = tid >> 15;
    const int h = (int)(rest & 7);
    const int b = (int)(rest >> 3);
    float* base = qkv + ((long)b * 768 + h * 32) * NTOK + tok;

    float vals[32];
    float m = -1e30f;
    #pragma unroll
    for (int d = 0; d < 32; ++d) { vals[d] = base[(long)d * NTOK]; m = fmaxf(m, vals[d]); }
    float s = 0.f;
    #pragma unroll
    for (int d = 0; d < 32; ++d) { vals[d] = __expf(vals[d] - m); s += vals[d]; }
    const float inv = 1.0f / s;
    #pragma unroll
    for (int d = 0; d < 32; ++d) base[(long)d * NTOK] = vals[d] * inv;
}

// ---------------------------------------------------------------------------
// W2[b][o][h*32+d] = (sum_e w_out[o, h*32+e] * num[b,h,d,e]) / den[b, h*32+d]
// ---------------------------------------------------------------------------
__global__ __launch_bounds__(256) void combine_kernel(
    const float* __restrict__ w_out, const float* __restrict__ num,
    const float* __restrict__ den, float* __restrict__ W2)
{
    const int tid = blockIdx.x * 256 + threadIdx.x;   // 2*256*256 total
    const int b = tid >> 16;
    const int rem = tid & 65535;
    const int o = rem >> 8;
    const int i = rem & 255;
    const int h = i >> 5, d = i & 31;
    const float* wrow = w_out + o * 256 + h * 32;
    const float* nrow = num + (((long)(b * 8 + h) * 32 + d) << 5);
    float s = 0.f;
    #pragma unroll
    for (int e = 0; e < 32; ++e) s += wrow[e] * nrow[e];
    W2[tid] = s / den[b * 256 + h * 32 + d];
}

// ---------------------------------------------------------------------------
extern "C" void kernel_launch(void* const* d_in, const int* in_sizes, int n_in,
                              void* d_out, int out_size, void* d_ws, size_t ws_size,
                              hipStream_t stream)
{
    const float* x     = (const float*)d_in[0];   // [2,256,32,32,32]
    const float* w_qkv = (const float*)d_in[1];   // [768,256]
    const float* w_out = (const float*)d_in[2];   // [256,256]
    float* out = (float*)d_out;                   // [2,256,32768]

    // workspace layout (floats)
    float* qkv  = (float*)d_ws;                   // 2*768*32768
    const long qkv_elems = 2L * 768 * NTOK;
    float* kmax = qkv + qkv_elems;                // 512
    float* num  = kmax + 512;                     // 2*8*32*32 = 16384
    float* den  = num + 16384;                    // 512
    float* W2   = den + 512;                      // 2*256*256 = 131072

    // zero the atomic accumulators (num + den are contiguous)
    hipMemsetAsync(num, 0, (16384 + 512) * sizeof(float), stream);

    // 1) qkv = w_qkv @ x   [768 x 32768, K=256] x2 batches
    gemm_tiled<<<dim3(NTOK / 64, 768 / 64, 2), 256, 0, stream>>>(
        w_qkv, x, qkv, 768, NTOK, 256, 0L, 256L * NTOK, 768L * NTOK);

    // 2) per-channel k max over tokens
    kmax_kernel<<<512, 256, 0, stream>>>(qkv, kmax);

    // 3) context numerator/denominator
    ctx_kernel<<<dim3(16, 8, 2), 256, 0, stream>>>(qkv, kmax, num, den, NTOK / 16);

    // 4) q softmax (in place on qkv rows 0..255)
    qsoft_kernel<<<(2L * 8 * NTOK) / 256, 256, 0, stream>>>(qkv);

    // 5) fold w_out with context -> per-batch W2 [256 x 256]
    combine_kernel<<<512, 256, 0, stream>>>(w_out, num, den, W2);

    // 6) out = W2 @ q_soft   [256 x 32768, K=256] x2 batches
    gemm_tiled<<<dim3(NTOK / 64, 256 / 64, 2), 256, 0, stream>>>(
        W2, qkv, out, 256, NTOK, 256, 65536L, 768L * NTOK, 256L * NTOK);
}

// Round 2
// 302.392 us; speedup vs baseline: 2.2018x; 2.2018x over previous
//
#include <hip/hip_runtime.h>

#define NTOK 32768

typedef __attribute__((ext_vector_type(8))) short  bf16x8;
typedef __attribute__((ext_vector_type(8))) unsigned short u16x8;
typedef __attribute__((ext_vector_type(4))) float  f32x4;

__device__ __forceinline__ unsigned short f32_to_bf16(float f) {
    unsigned int u = __float_as_uint(f);
    u += 0x7FFFu + ((u >> 16) & 1u);          // round-to-nearest-even
    return (unsigned short)(u >> 16);
}
__device__ __forceinline__ float bf16_to_f32(unsigned short h) {
    return __uint_as_float(((unsigned int)h) << 16);
}

// ---------------------------------------------------------------------------
// MFMA GEMM: C[M,NTOK] = A[M,256] * B[256,NTOK].
// A: bf16 row-major (K contiguous), staged via LDS.
// B: fp32 or bf16, [K][N] row-major — fragments loaded DIRECTLY from global
//    (8 strided k-loads per lane; lanes 0-15 span 16 consecutive n = coalesced).
// Tile 128x128, 4 waves in 2x2, each wave 4x4 MFMA tiles of 16x16x32.
// ---------------------------------------------------------------------------
template <typename BT, typename CT>
__global__ __launch_bounds__(256) void gemm_mfma(
    const unsigned short* __restrict__ A, const BT* __restrict__ B,
    CT* __restrict__ C, int M, long sA, long sB, long sC)
{
    const int bz = blockIdx.z;
    A += (long)bz * sA; B += (long)bz * sB; C += (long)bz * sC;
    const int row0 = blockIdx.x * 128;   // x = m-block so consecutive blocks share B cols (L2)
    const int col0 = blockIdx.y * 128;

    __shared__ unsigned short As[128 * 40];   // pitch 40 bf16 breaks bank stride

    const int t = threadIdx.x;
    const int wave = t >> 6, lane = t & 63;
    const int wm = wave >> 1, wn = wave & 1;
    const int m16 = lane & 15, quad = lane >> 4;

    const int sr = t >> 2;       // staging row 0..63 (+64 second pass)
    const int sseg = t & 3;      // 16B segment within 64B row chunk

    f32x4 acc[4][4] = {};

    for (int kk = 0; kk < 8; ++kk) {
        const int k0 = kk * 32;

        __syncthreads();   // previous iteration's As readers done

        // ---- issue A staging global loads
        bf16x8 a_ld[2];
        #pragma unroll
        for (int h = 0; h < 2; ++h) {
            const int r = sr + h * 64;
            a_ld[h] = *(const bf16x8*)&A[(size_t)(row0 + r) * 256 + k0 + sseg * 8];
        }

        // ---- B fragments direct from global (fp32 -> cvt, or bf16 raw)
        bf16x8 bf[4];
        const BT* bp = B + (size_t)(k0 + quad * 8) * NTOK + col0 + wn * 64 + m16;
        #pragma unroll
        for (int nt = 0; nt < 4; ++nt) {
            const BT* bpn = bp + nt * 16;
            #pragma unroll
            for (int j = 0; j < 8; ++j) {
                BT v = bpn[(size_t)j * NTOK];
                if constexpr (sizeof(BT) == 4)
                    bf[nt][j] = (short)f32_to_bf16((float)v);
                else
                    bf[nt][j] = (short)(unsigned short)v;
            }
        }

        // ---- write A tile to LDS
        #pragma unroll
        for (int h = 0; h < 2; ++h) {
            const int r = sr + h * 64;
            *(bf16x8*)&As[r * 40 + sseg * 8] = a_ld[h];
        }
        __syncthreads();

        // ---- A fragments from LDS
        bf16x8 af[4];
        #pragma unroll
        for (int mt = 0; mt < 4; ++mt)
            af[mt] = *(const bf16x8*)&As[(wm * 64 + mt * 16 + m16) * 40 + quad * 8];

        #pragma unroll
        for (int mt = 0; mt < 4; ++mt)
            #pragma unroll
            for (int nt = 0; nt < 4; ++nt)
                acc[mt][nt] = __builtin_amdgcn_mfma_f32_16x16x32_bf16(
                    af[mt], bf[nt], acc[mt][nt], 0, 0, 0);
    }

    // ---- epilogue: D[row][col], col = lane&15, row = quad*4 + r
    #pragma unroll
    for (int mt = 0; mt < 4; ++mt) {
        #pragma unroll
        for (int nt = 0; nt < 4; ++nt) {
            #pragma unroll
            for (int r = 0; r < 4; ++r) {
                const int row = row0 + wm * 64 + mt * 16 + quad * 4 + r;
                const int col = col0 + wn * 64 + nt * 16 + m16;
                if constexpr (sizeof(CT) == 4)
                    C[(size_t)row * NTOK + col] = acc[mt][nt][r];
                else
                    C[(size_t)row * NTOK + col] = f32_to_bf16(acc[mt][nt][r]);
            }
        }
    }
}

// ---------------------------------------------------------------------------
// fp32 -> bf16 cast (vectorized), n multiple of 1024
// ---------------------------------------------------------------------------
__global__ __launch_bounds__(256) void cast_bf16_kernel(
    const float* __restrict__ src, unsigned short* __restrict__ dst, int n4)
{
    const int i = blockIdx.x * 256 + threadIdx.x;
    if (i < n4) {
        float4 v = ((const float4*)src)[i];
        ushort4 o;
        o.x = f32_to_bf16(v.x); o.y = f32_to_bf16(v.y);
        o.z = f32_to_bf16(v.z); o.w = f32_to_bf16(v.w);
        ((ushort4*)dst)[i] = o;
    }
}

// ---------------------------------------------------------------------------
// Per-(batch, k-channel) max over n (bf16 input). One block per channel.
// ---------------------------------------------------------------------------
__global__ __launch_bounds__(256) void kmax_kernel(
    const unsigned short* __restrict__ qkv, float* __restrict__ kmax)
{
    const int bc = blockIdx.x;            // b*256 + ch
    const int b = bc >> 8, ch = bc & 255;
    const unsigned short* row = qkv + ((long)b * 768 + 256 + ch) * NTOK;
    float m = -1e30f;
    for (int i = threadIdx.x * 8; i < NTOK; i += 256 * 8) {
        u16x8 v = *(const u16x8*)&row[i];
        #pragma unroll
        for (int j = 0; j < 8; ++j) m = fmaxf(m, bf16_to_f32(v[j]));
    }
    #pragma unroll
    for (int off = 32; off > 0; off >>= 1) m = fmaxf(m, __shfl_down(m, off, 64));
    __shared__ float sm[4];
    if ((threadIdx.x & 63) == 0) sm[threadIdx.x >> 6] = m;
    __syncthreads();
    if (threadIdx.x == 0)
        kmax[bc] = fmaxf(fmaxf(sm[0], sm[1]), fmaxf(sm[2], sm[3]));
}

// ---------------------------------------------------------------------------
// context num[b,h,d,e] = sum_n exp(k[n,d]-kmax[d]) * v[n,e]; den = sum exp.
// bf16 inputs; fp32 LDS tiles; atomic partial combine.
// ---------------------------------------------------------------------------
#define CTILE 128
__global__ __launch_bounds__(256) void ctx_kernel(
    const unsigned short* __restrict__ qkv, const float* __restrict__ kmax,
    float* __restrict__ num, float* __restrict__ den, int tokens_per_block)
{
    const int chunk = blockIdx.x, h = blockIdx.y, b = blockIdx.z;
    const int n0 = chunk * tokens_per_block;
    const unsigned short* kbase = qkv + ((long)b * 768 + 256 + h * 32) * NTOK;
    const unsigned short* vbase = qkv + ((long)b * 768 + 512 + h * 32) * NTOK;

    __shared__ float ks[32][CTILE + 2];   // pitch 130: banks (2d+tok) -> 2-way (free)
    __shared__ float vs[32][CTILE + 2];

    const int t = threadIdx.x;
    const int d = t >> 3, eg = t & 7;     // compute mapping
    const int lrow = t >> 3, lf = t & 7;  // load mapping: row, vec8 group
    const float km = kmax[b * 256 + h * 32 + lrow];

    float acc[4] = {0.f, 0.f, 0.f, 0.f};
    float dsum = 0.f;

    for (int tile = 0; tile < tokens_per_block; tile += CTILE) {
        #pragma unroll
        for (int j = 0; j < 2; ++j) {
            const int f = lf * 2 + j;     // vec8 index 0..15 within row
            const long g = (long)lrow * NTOK + n0 + tile + f * 8;
            u16x8 kv = *(const u16x8*)&kbase[g];
            u16x8 vv = *(const u16x8*)&vbase[g];
            #pragma unroll
            for (int e = 0; e < 8; ++e) {
                ks[lrow][f * 8 + e] = __expf(bf16_to_f32(kv[e]) - km);
                vs[lrow][f * 8 + e] = bf16_to_f32(vv[e]);
            }
        }
        __syncthreads();
        for (int tok = 0; tok < CTILE; ++tok) {
            const float ek = ks[d][tok];
            dsum += ek;
            #pragma unroll
            for (int i = 0; i < 4; ++i) acc[i] += ek * vs[eg * 4 + i][tok];
        }
        __syncthreads();
    }
    float* nrow = num + (((long)(b * 8 + h) * 32 + d) * 32);
    #pragma unroll
    for (int i = 0; i < 4; ++i) atomicAdd(&nrow[eg * 4 + i], acc[i]);
    if (eg == 0) atomicAdd(&den[b * 256 + h * 32 + d], dsum);
}

// ---------------------------------------------------------------------------
// q softmax over Dh=32, in place on bf16 q rows. One thread per (b,h,token).
// ---------------------------------------------------------------------------
__global__ __launch_bounds__(256) void qsoft_kernel(unsigned short* __restrict__ qkv)
{
    const long tid = (long)blockIdx.x * 256 + threadIdx.x;  // over b*8*NTOK
    const int tok = (int)(tid & (NTOK - 1));
    const long rest = tid >> 15;
    const int h = (int)(rest & 7);
    const int b = (int)(rest >> 3);
    unsigned short* base = qkv + ((long)b * 768 + h * 32) * NTOK + tok;

    float vals[32];
    float m = -1e30f;
    #pragma unroll
    for (int d = 0; d < 32; ++d) {
        vals[d] = bf16_to_f32(base[(long)d * NTOK]);
        m = fmaxf(m, vals[d]);
    }
    float s = 0.f;
    #pragma unroll
    for (int d = 0; d < 32; ++d) { vals[d] = __expf(vals[d] - m); s += vals[d]; }
    const float inv = 1.0f / s;
    #pragma unroll
    for (int d = 0; d < 32; ++d) base[(long)d * NTOK] = f32_to_bf16(vals[d] * inv);
}

// ---------------------------------------------------------------------------
// W2[b][o][h*32+d] = (sum_e w_out[o,h*32+e] * num[b,h,d,e]) / den[b,h*32+d]
// output bf16 (A operand of GEMM2)
// ---------------------------------------------------------------------------
__global__ __launch_bounds__(256) void combine_kernel(
    const float* __restrict__ w_out, const float* __restrict__ num,
    const float* __restrict__ den, unsigned short* __restrict__ W2)
{
    const int tid = blockIdx.x * 256 + threadIdx.x;   // 2*256*256 total
    const int b = tid >> 16;
    const int rem = tid & 65535;
    const int o = rem >> 8;
    const int i = rem & 255;
    const int h = i >> 5, d = i & 31;
    const float* wrow = w_out + o * 256 + h * 32;
    const float* nrow = num + (((long)(b * 8 + h) * 32 + d) << 5);
    float s = 0.f;
    #pragma unroll
    for (int e = 0; e < 32; ++e) s += wrow[e] * nrow[e];
    W2[tid] = f32_to_bf16(s / den[b * 256 + h * 32 + d]);
}

// ---------------------------------------------------------------------------
extern "C" void kernel_launch(void* const* d_in, const int* in_sizes, int n_in,
                              void* d_out, int out_size, void* d_ws, size_t ws_size,
                              hipStream_t stream)
{
    const float* x     = (const float*)d_in[0];   // [2,256,32768]
    const float* w_qkv = (const float*)d_in[1];   // [768,256]
    const float* w_out = (const float*)d_in[2];   // [256,256]
    float* out = (float*)d_out;                   // [2,256,32768]

    // workspace layout
    unsigned short* qkv_bf = (unsigned short*)d_ws;           // 2*768*32768 bf16
    const long qkv_elems = 2L * 768 * NTOK;
    unsigned short* wqkv_bf = qkv_bf + qkv_elems;             // 768*256 bf16
    unsigned short* W2 = wqkv_bf + 768 * 256;                 // 2*256*256 bf16
    float* kmax = (float*)(W2 + 2 * 256 * 256);               // 512
    float* num  = kmax + 512;                                 // 16384
    float* den  = num + 16384;                                // 512

    hipMemsetAsync(num, 0, (16384 + 512) * sizeof(float), stream);

    // 0) cast w_qkv to bf16
    cast_bf16_kernel<<<192, 256, 0, stream>>>(w_qkv, wqkv_bf, 768 * 256 / 4);

    // 1) qkv_bf16 = w_qkv_bf16 @ x(fp32)   [768 x 32768, K=256] x2
    gemm_mfma<float, unsigned short><<<dim3(6, 256, 2), 256, 0, stream>>>(
        wqkv_bf, x, qkv_bf, 768, 0L, 256L * NTOK, 768L * NTOK);

    // 2) per-channel k max
    kmax_kernel<<<512, 256, 0, stream>>>(qkv_bf, kmax);

    // 3) context num/den
    ctx_kernel<<<dim3(16, 8, 2), 256, 0, stream>>>(qkv_bf, kmax, num, den, NTOK / 16);

    // 4) q softmax in place (bf16)
    qsoft_kernel<<<(2L * 8 * NTOK) / 256, 256, 0, stream>>>(qkv_bf);

    // 5) W2 = fold(w_out, context) -> bf16
    combine_kernel<<<512, 256, 0, stream>>>(w_out, num, den, W2);

    // 6) out(fp32) = W2(bf16) @ q_soft(bf16)   [256 x 32768, K=256] x2
    gemm_mfma<unsigned short, float><<<dim3(2, 256, 2), 256, 0, stream>>>(
        W2, qkv_bf, out, 256, 65536L, 768L * NTOK, 256L * NTOK);
}

// Round 3
// 276.583 us; speedup vs baseline: 2.4073x; 1.0933x over previous
//
#include <hip/hip_runtime.h>

#define NTOK 32768

typedef __attribute__((ext_vector_type(8))) short  bf16x8;
typedef __attribute__((ext_vector_type(8))) unsigned short u16x8;
typedef __attribute__((ext_vector_type(4))) float  f32x4;

__device__ __forceinline__ unsigned short f32_to_bf16(float f) {
    unsigned int u = __float_as_uint(f);
    u += 0x7FFFu + ((u >> 16) & 1u);          // round-to-nearest-even
    return (unsigned short)(u >> 16);
}
__device__ __forceinline__ float bf16_to_f32(unsigned short h) {
    return __uint_as_float(((unsigned int)h) << 16);
}

// ---------------------------------------------------------------------------
// MFMA GEMM: C[M,NTOK] = A[M,256] * B[256,NTOK].
// A: bf16 row-major (K contiguous), staged via LDS.
// B: fp32 or bf16 [K][N] row-major — fragments loaded directly from global
//    (8 strided k-loads per lane; lanes 0-15 span 16 consecutive n = coalesced).
// Tile 128x128. Wave layout 1x4: wave wn owns a 32-col strip, computes
// 8 mt x 2 nt MFMA tiles of 16x16x32 -> no cross-wave B redundancy,
// 16 B-loads per thread per k-step (was 32).
// QSOFT: for blocks with row0 < 256 (q rows), apply softmax over each head's
// 32 m-rows in-register before the write (quad reduction via shfl_xor 16/32).
// ---------------------------------------------------------------------------
template <typename BT, typename CT, bool QSOFT>
__global__ __launch_bounds__(256) void gemm_mfma(
    const unsigned short* __restrict__ A, const BT* __restrict__ B,
    CT* __restrict__ C, long sA, long sB, long sC)
{
    const int bz = blockIdx.z;
    A += (long)bz * sA; B += (long)bz * sB; C += (long)bz * sC;
    const int row0 = blockIdx.x * 128;   // x = m-block so consecutive blocks share B cols (L2)
    const int col0 = blockIdx.y * 128;

    __shared__ unsigned short As[128 * 40];   // pitch 40 bf16: 80B row stride, 2-way free

    const int t = threadIdx.x;
    const int wn = t >> 6, lane = t & 63;
    const int m16 = lane & 15, quad = lane >> 4;

    const int sr = t >> 2;       // staging row 0..63 (+64 second pass)
    const int sseg = t & 3;      // 16B segment within 64B row chunk

    f32x4 acc[8][2] = {};

    for (int kk = 0; kk < 8; ++kk) {
        const int k0 = kk * 32;

        __syncthreads();   // previous iteration's As readers done

        // ---- issue A staging global loads
        bf16x8 a_ld[2];
        #pragma unroll
        for (int h = 0; h < 2; ++h)
            a_ld[h] = *(const bf16x8*)&A[(size_t)(row0 + sr + h * 64) * 256 + k0 + sseg * 8];

        // ---- B fragments direct from global (fp32 -> cvt, or bf16 raw)
        bf16x8 bf[2];
        const BT* bp = B + (size_t)(k0 + quad * 8) * NTOK + col0 + wn * 32 + m16;
        #pragma unroll
        for (int nt = 0; nt < 2; ++nt) {
            const BT* bpn = bp + nt * 16;
            #pragma unroll
            for (int j = 0; j < 8; ++j) {
                BT v = bpn[(size_t)j * NTOK];
                if constexpr (sizeof(BT) == 4)
                    bf[nt][j] = (short)f32_to_bf16((float)v);
                else
                    bf[nt][j] = (short)(unsigned short)v;
            }
        }

        // ---- write A tile to LDS
        #pragma unroll
        for (int h = 0; h < 2; ++h)
            *(bf16x8*)&As[(sr + h * 64) * 40 + sseg * 8] = a_ld[h];
        __syncthreads();

        // ---- A fragments from LDS + MFMA
        #pragma unroll
        for (int mt = 0; mt < 8; ++mt) {
            const bf16x8 af = *(const bf16x8*)&As[(mt * 16 + m16) * 40 + quad * 8];
            #pragma unroll
            for (int nt = 0; nt < 2; ++nt)
                acc[mt][nt] = __builtin_amdgcn_mfma_f32_16x16x32_bf16(
                    af, bf[nt], acc[mt][nt], 0, 0, 0);
        }
    }

    // ---- fused q softmax: over each head's 32 rows (= mt pair x 4 quads x 4 r)
    if (QSOFT && row0 < 256) {
        #pragma unroll
        for (int hj = 0; hj < 4; ++hj) {
            #pragma unroll
            for (int nt = 0; nt < 2; ++nt) {
                float mx = -1e30f;
                #pragma unroll
                for (int p = 0; p < 2; ++p)
                    #pragma unroll
                    for (int r = 0; r < 4; ++r)
                        mx = fmaxf(mx, acc[hj * 2 + p][nt][r]);
                mx = fmaxf(mx, __shfl_xor(mx, 16, 64));
                mx = fmaxf(mx, __shfl_xor(mx, 32, 64));
                float s = 0.f;
                #pragma unroll
                for (int p = 0; p < 2; ++p)
                    #pragma unroll
                    for (int r = 0; r < 4; ++r) {
                        const float e = __expf(acc[hj * 2 + p][nt][r] - mx);
                        acc[hj * 2 + p][nt][r] = e;
                        s += e;
                    }
                s += __shfl_xor(s, 16, 64);
                s += __shfl_xor(s, 32, 64);
                const float inv = 1.0f / s;
                #pragma unroll
                for (int p = 0; p < 2; ++p)
                    #pragma unroll
                    for (int r = 0; r < 4; ++r)
                        acc[hj * 2 + p][nt][r] *= inv;
            }
        }
    }

    // ---- epilogue: D[row][col], col = lane&15, row = quad*4 + r
    #pragma unroll
    for (int mt = 0; mt < 8; ++mt) {
        #pragma unroll
        for (int nt = 0; nt < 2; ++nt) {
            #pragma unroll
            for (int r = 0; r < 4; ++r) {
                const int row = row0 + mt * 16 + quad * 4 + r;
                const int col = col0 + wn * 32 + nt * 16 + m16;
                if constexpr (sizeof(CT) == 4)
                    C[(size_t)row * NTOK + col] = acc[mt][nt][r];
                else
                    C[(size_t)row * NTOK + col] = f32_to_bf16(acc[mt][nt][r]);
            }
        }
    }
}

// ---------------------------------------------------------------------------
// fp32 -> bf16 cast (vectorized)
// ---------------------------------------------------------------------------
__global__ __launch_bounds__(256) void cast_bf16_kernel(
    const float* __restrict__ src, unsigned short* __restrict__ dst, int n4)
{
    const int i = blockIdx.x * 256 + threadIdx.x;
    if (i < n4) {
        float4 v = ((const float4*)src)[i];
        ushort4 o;
        o.x = f32_to_bf16(v.x); o.y = f32_to_bf16(v.y);
        o.z = f32_to_bf16(v.z); o.w = f32_to_bf16(v.w);
        ((ushort4*)dst)[i] = o;
    }
}

// ---------------------------------------------------------------------------
// context num[b,h,d,e] = sum_n exp(k[n,d]) * v[n,e]; den = sum_n exp(k[n,d]).
// No max subtraction: k ~ N(0, 0.32^2) so exp(k) is tiny-range, fp32-safe,
// and softmax is shift-invariant (matches reference exactly in exact math).
// bf16 inputs; fp32 LDS tiles; atomic partial combine.
// ---------------------------------------------------------------------------
#define CTILE 128
__global__ __launch_bounds__(256) void ctx_kernel(
    const unsigned short* __restrict__ qkv,
    float* __restrict__ num, float* __restrict__ den, int tokens_per_block)
{
    const int chunk = blockIdx.x, h = blockIdx.y, b = blockIdx.z;
    const int n0 = chunk * tokens_per_block;
    const unsigned short* kbase = qkv + ((long)b * 768 + 256 + h * 32) * NTOK;
    const unsigned short* vbase = qkv + ((long)b * 768 + 512 + h * 32) * NTOK;

    __shared__ float ks[32][CTILE + 2];   // pitch 130: 2-way bank alias (free)
    __shared__ float vs[32][CTILE + 2];

    const int t = threadIdx.x;
    const int d = t >> 3, eg = t & 7;     // compute mapping
    const int lrow = t >> 3, lf = t & 7;  // load mapping: row, vec8 group

    float acc[4] = {0.f, 0.f, 0.f, 0.f};
    float dsum = 0.f;

    for (int tile = 0; tile < tokens_per_block; tile += CTILE) {
        #pragma unroll
        for (int j = 0; j < 2; ++j) {
            const int f = lf * 2 + j;     // vec8 index 0..15 within row
            const long g = (long)lrow * NTOK + n0 + tile + f * 8;
            u16x8 kv = *(const u16x8*)&kbase[g];
            u16x8 vv = *(const u16x8*)&vbase[g];
            #pragma unroll
            for (int e = 0; e < 8; ++e) {
                ks[lrow][f * 8 + e] = __expf(bf16_to_f32(kv[e]));
                vs[lrow][f * 8 + e] = bf16_to_f32(vv[e]);
            }
        }
        __syncthreads();
        for (int tok = 0; tok < CTILE; ++tok) {
            const float ek = ks[d][tok];
            dsum += ek;
            #pragma unroll
            for (int i = 0; i < 4; ++i) acc[i] += ek * vs[eg * 4 + i][tok];
        }
        __syncthreads();
    }
    float* nrow = num + (((long)(b * 8 + h) * 32 + d) * 32);
    #pragma unroll
    for (int i = 0; i < 4; ++i) atomicAdd(&nrow[eg * 4 + i], acc[i]);
    if (eg == 0) atomicAdd(&den[b * 256 + h * 32 + d], dsum);
}

// ---------------------------------------------------------------------------
// W2[b][o][h*32+d] = (sum_e w_out[o,h*32+e] * num[b,h,d,e]) / den[b,h*32+d]
// output bf16 (A operand of GEMM2)
// ---------------------------------------------------------------------------
__global__ __launch_bounds__(256) void combine_kernel(
    const float* __restrict__ w_out, const float* __restrict__ num,
    const float* __restrict__ den, unsigned short* __restrict__ W2)
{
    const int tid = blockIdx.x * 256 + threadIdx.x;   // 2*256*256 total
    const int b = tid >> 16;
    const int rem = tid & 65535;
    const int o = rem >> 8;
    const int i = rem & 255;
    const int h = i >> 5, d = i & 31;
    const float* wrow = w_out + o * 256 + h * 32;
    const float* nrow = num + (((long)(b * 8 + h) * 32 + d) << 5);
    float s = 0.f;
    #pragma unroll
    for (int e = 0; e < 32; ++e) s += wrow[e] * nrow[e];
    W2[tid] = f32_to_bf16(s / den[b * 256 + h * 32 + d]);
}

// ---------------------------------------------------------------------------
extern "C" void kernel_launch(void* const* d_in, const int* in_sizes, int n_in,
                              void* d_out, int out_size, void* d_ws, size_t ws_size,
                              hipStream_t stream)
{
    const float* x     = (const float*)d_in[0];   // [2,256,32768]
    const float* w_qkv = (const float*)d_in[1];   // [768,256]
    const float* w_out = (const float*)d_in[2];   // [256,256]
    float* out = (float*)d_out;                   // [2,256,32768]

    // workspace layout
    unsigned short* qkv_bf = (unsigned short*)d_ws;           // 2*768*32768 bf16
    const long qkv_elems = 2L * 768 * NTOK;
    unsigned short* wqkv_bf = qkv_bf + qkv_elems;             // 768*256 bf16
    unsigned short* W2 = wqkv_bf + 768 * 256;                 // 2*256*256 bf16
    float* num  = (float*)(W2 + 2 * 256 * 256);               // 16384
    float* den  = num + 16384;                                // 512

    hipMemsetAsync(num, 0, (16384 + 512) * sizeof(float), stream);

    // 0) cast w_qkv to bf16
    cast_bf16_kernel<<<192, 256, 0, stream>>>(w_qkv, wqkv_bf, 768 * 256 / 4);

    // 1) qkv = w_qkv @ x, q rows softmax'd in-epilogue  [768 x 32768, K=256] x2
    gemm_mfma<float, unsigned short, true><<<dim3(6, 256, 2), 256, 0, stream>>>(
        wqkv_bf, x, qkv_bf, 0L, 256L * NTOK, 768L * NTOK);

    // 2) context num/den (no kmax pass)
    ctx_kernel<<<dim3(16, 8, 2), 256, 0, stream>>>(qkv_bf, num, den, NTOK / 16);

    // 3) W2 = fold(w_out, context) -> bf16
    combine_kernel<<<512, 256, 0, stream>>>(w_out, num, den, W2);

    // 4) out(fp32) = W2(bf16) @ q_soft(bf16)   [256 x 32768, K=256] x2
    gemm_mfma<unsigned short, float, false><<<dim3(2, 256, 2), 256, 0, stream>>>(
        W2, qkv_bf, out, 65536L, 768L * NTOK, 256L * NTOK);
}

// Round 4
// 271.630 us; speedup vs baseline: 2.4512x; 1.0182x over previous
//
#include <hip/hip_runtime.h>

#define NTOK 32768

typedef __attribute__((ext_vector_type(8))) short  bf16x8;
typedef __attribute__((ext_vector_type(8))) unsigned short u16x8;
typedef __attribute__((ext_vector_type(4))) float  f32x4;

__device__ __forceinline__ unsigned short f32_to_bf16(float f) {
    unsigned int u = __float_as_uint(f);
    u += 0x7FFFu + ((u >> 16) & 1u);          // round-to-nearest-even
    return (unsigned short)(u >> 16);
}
__device__ __forceinline__ float bf16_to_f32(unsigned short h) {
    return __uint_as_float(((unsigned int)h) << 16);
}

// ---------------------------------------------------------------------------
// B-stationary MFMA GEMM: C[M,NTOK] = A[M,256] * B[256,NTOK].
// One block per 128-col strip (x) per batch (y): B tile [256k][128n] is
// fetched from HBM EXACTLY ONCE, converted to bf16, stored transposed in LDS
// (Bs[n][k], 16B-granule XOR swizzle -> uniform banks on both write & read).
// Then loop over MCHUNKS m-chunks of 128 rows; A fragments are gathered
// directly from global (16 rows x 64B dense lines per inst; A is tiny and
// L2-resident), so the K-loop has no barriers at all.
// Waves 2x2: each wave = 64 rows x 64 cols = 4 mt x 4 nt MFMA tiles.
// QSOFT: m-chunks 0,1 are q rows -> softmax over each head's 32 rows
// in-register (mt-pair + quad reduction via shfl_xor 16/32) before store.
// ---------------------------------------------------------------------------
template <typename BT, typename CT, int MCHUNKS, bool QSOFT>
__global__ __launch_bounds__(256) void gemm_bstat(
    const unsigned short* __restrict__ A, const BT* __restrict__ B,
    CT* __restrict__ C, long sA, long sB, long sC)
{
    const int bz = blockIdx.y;
    A += (long)bz * sA; B += (long)bz * sB; C += (long)bz * sC;
    const int col0 = blockIdx.x * 128;

    __shared__ unsigned short Bs[128 * 256];   // 64 KB

    const int t = threadIdx.x;
    const int wave = t >> 6, lane = t & 63;
    const int wm = wave >> 1, wn = wave & 1;
    const int m16 = lane & 15, quad = lane >> 4;

    // ---- stage B tile once: [256k][128n] fp32/bf16 -> Bs[n][256k] bf16
    {
        const int n = t & 127;                  // waves 0,1 -> n 0..127, k-half 0
        const int kg0 = (t >> 7) * 16;          // waves 2,3 -> k-half 1
        const int key = n & 7;
        const BT* bcol = B + col0 + n;
        #pragma unroll
        for (int g = 0; g < 16; ++g) {
            const int kg = kg0 + g;             // 16B granule index along k (0..31)
            unsigned short tmp[8];
            #pragma unroll
            for (int i = 0; i < 8; ++i) {
                BT v = bcol[(size_t)(kg * 8 + i) * NTOK];
                if constexpr (sizeof(BT) == 4) tmp[i] = f32_to_bf16((float)v);
                else                           tmp[i] = (unsigned short)v;
            }
            *(u16x8*)&Bs[n * 256 + ((kg ^ key) * 8)] = *(const u16x8*)tmp;
        }
    }
    __syncthreads();   // the only barrier

    const int swk = m16 & 7;

    for (int mc = 0; mc < MCHUNKS; ++mc) {
        const int m0 = mc * 128;
        f32x4 acc[4][4] = {};

        // lane-base pointer into A for this chunk's fragments
        const unsigned short* Abase = A + (size_t)(m0 + wm * 64 + m16) * 256 + quad * 8;

        #pragma unroll
        for (int kk = 0; kk < 8; ++kk) {
            bf16x8 bf[4];
            #pragma unroll
            for (int nt = 0; nt < 4; ++nt) {
                const int col = wn * 64 + nt * 16 + m16;
                bf[nt] = *(const bf16x8*)&Bs[col * 256 + (((kk * 4 + quad) ^ swk) * 8)];
            }
            #pragma unroll
            for (int mt = 0; mt < 4; ++mt) {
                const bf16x8 af = *(const bf16x8*)&Abase[(size_t)mt * 16 * 256 + kk * 32];
                #pragma unroll
                for (int nt = 0; nt < 4; ++nt)
                    acc[mt][nt] = __builtin_amdgcn_mfma_f32_16x16x32_bf16(
                        af, bf[nt], acc[mt][nt], 0, 0, 0);
            }
        }

        // ---- fused q softmax over each head's 32 rows (chunks 0,1 = q rows)
        if (QSOFT && m0 < 256) {
            #pragma unroll
            for (int hj = 0; hj < 2; ++hj) {       // 2 heads per wave (64 rows)
                #pragma unroll
                for (int nt = 0; nt < 4; ++nt) {
                    float mx = -1e30f;
                    #pragma unroll
                    for (int p = 0; p < 2; ++p)
                        #pragma unroll
                        for (int r = 0; r < 4; ++r)
                            mx = fmaxf(mx, acc[hj * 2 + p][nt][r]);
                    mx = fmaxf(mx, __shfl_xor(mx, 16, 64));
                    mx = fmaxf(mx, __shfl_xor(mx, 32, 64));
                    float s = 0.f;
                    #pragma unroll
                    for (int p = 0; p < 2; ++p)
                        #pragma unroll
                        for (int r = 0; r < 4; ++r) {
                            const float e = __expf(acc[hj * 2 + p][nt][r] - mx);
                            acc[hj * 2 + p][nt][r] = e;
                            s += e;
                        }
                    s += __shfl_xor(s, 16, 64);
                    s += __shfl_xor(s, 32, 64);
                    const float inv = 1.0f / s;
                    #pragma unroll
                    for (int p = 0; p < 2; ++p)
                        #pragma unroll
                        for (int r = 0; r < 4; ++r)
                            acc[hj * 2 + p][nt][r] *= inv;
                }
            }
        }

        // ---- store: D[row][col], col = lane&15, row = quad*4 + r
        #pragma unroll
        for (int mt = 0; mt < 4; ++mt) {
            #pragma unroll
            for (int nt = 0; nt < 4; ++nt) {
                #pragma unroll
                for (int r = 0; r < 4; ++r) {
                    const int row = m0 + wm * 64 + mt * 16 + quad * 4 + r;
                    const int col = col0 + wn * 64 + nt * 16 + m16;
                    if constexpr (sizeof(CT) == 4)
                        C[(size_t)row * NTOK + col] = acc[mt][nt][r];
                    else
                        C[(size_t)row * NTOK + col] = f32_to_bf16(acc[mt][nt][r]);
                }
            }
        }
    }
}

// ---------------------------------------------------------------------------
// fp32 -> bf16 cast (vectorized)
// ---------------------------------------------------------------------------
__global__ __launch_bounds__(256) void cast_bf16_kernel(
    const float* __restrict__ src, unsigned short* __restrict__ dst, int n4)
{
    const int i = blockIdx.x * 256 + threadIdx.x;
    if (i < n4) {
        float4 v = ((const float4*)src)[i];
        ushort4 o;
        o.x = f32_to_bf16(v.x); o.y = f32_to_bf16(v.y);
        o.z = f32_to_bf16(v.z); o.w = f32_to_bf16(v.w);
        ((ushort4*)dst)[i] = o;
    }
}

// ---------------------------------------------------------------------------
// context num[b,h,d,e] = sum_n exp(k[n,d]) * v[n,e]; den = sum_n exp(k[n,d]).
// No max subtraction (k is small-range; softmax shift-invariant).
// v staged [tok][e] so the inner loop reads one b128 (8 distinct addrs,
// broadcast across lanes) instead of 4 scalar b32.
// ---------------------------------------------------------------------------
#define CTILE 128
__global__ __launch_bounds__(256) void ctx_kernel(
    const unsigned short* __restrict__ qkv,
    float* __restrict__ num, float* __restrict__ den, int tokens_per_block)
{
    const int chunk = blockIdx.x, h = blockIdx.y, b = blockIdx.z;
    const int n0 = chunk * tokens_per_block;
    const unsigned short* kbase = qkv + ((long)b * 768 + 256 + h * 32) * NTOK;
    const unsigned short* vbase = qkv + ((long)b * 768 + 512 + h * 32) * NTOK;

    __shared__ float ks[32][CTILE + 2];   // [d][tok]
    __shared__ float vs[CTILE][36];       // [tok][e], pitch 36 keeps float4 16B-aligned

    const int t = threadIdx.x;
    const int d = t >> 3, eg = t & 7;     // compute mapping
    const int lrow = t >> 3, lf = t & 7;  // load mapping

    float acc[4] = {0.f, 0.f, 0.f, 0.f};
    float dsum = 0.f;

    for (int tile = 0; tile < tokens_per_block; tile += CTILE) {
        #pragma unroll 4
        for (int jj = 0; jj < 16; ++jj) {
            const int tok = lf + 8 * jj;          // bank-friendly write pattern
            const long g = (long)lrow * NTOK + n0 + tile + tok;
            ks[lrow][tok] = __expf(bf16_to_f32(kbase[g]));
            vs[tok][lrow] = bf16_to_f32(vbase[g]);
        }
        __syncthreads();
        for (int tok = 0; tok < CTILE; ++tok) {
            const float ek = ks[d][tok];
            dsum += ek;
            const float4 vv = *(const float4*)&vs[tok][eg * 4];
            acc[0] += ek * vv.x; acc[1] += ek * vv.y;
            acc[2] += ek * vv.z; acc[3] += ek * vv.w;
        }
        __syncthreads();
    }
    float* nrow = num + (((long)(b * 8 + h) * 32 + d) * 32);
    #pragma unroll
    for (int i = 0; i < 4; ++i) atomicAdd(&nrow[eg * 4 + i], acc[i]);
    if (eg == 0) atomicAdd(&den[b * 256 + h * 32 + d], dsum);
}

// ---------------------------------------------------------------------------
// W2[b][o][h*32+d] = (sum_e w_out[o,h*32+e] * num[b,h,d,e]) / den[b,h*32+d]
// ---------------------------------------------------------------------------
__global__ __launch_bounds__(256) void combine_kernel(
    const float* __restrict__ w_out, const float* __restrict__ num,
    const float* __restrict__ den, unsigned short* __restrict__ W2)
{
    const int tid = blockIdx.x * 256 + threadIdx.x;   // 2*256*256 total
    const int b = tid >> 16;
    const int rem = tid & 65535;
    const int o = rem >> 8;
    const int i = rem & 255;
    const int h = i >> 5, d = i & 31;
    const float* wrow = w_out + o * 256 + h * 32;
    const float* nrow = num + (((long)(b * 8 + h) * 32 + d) << 5);
    float s = 0.f;
    #pragma unroll
    for (int e = 0; e < 32; ++e) s += wrow[e] * nrow[e];
    W2[tid] = f32_to_bf16(s / den[b * 256 + h * 32 + d]);
}

// ---------------------------------------------------------------------------
extern "C" void kernel_launch(void* const* d_in, const int* in_sizes, int n_in,
                              void* d_out, int out_size, void* d_ws, size_t ws_size,
                              hipStream_t stream)
{
    const float* x     = (const float*)d_in[0];   // [2,256,32768]
    const float* w_qkv = (const float*)d_in[1];   // [768,256]
    const float* w_out = (const float*)d_in[2];   // [256,256]
    float* out = (float*)d_out;                   // [2,256,32768]

    // workspace layout
    unsigned short* qkv_bf = (unsigned short*)d_ws;           // 2*768*32768 bf16
    const long qkv_elems = 2L * 768 * NTOK;
    unsigned short* wqkv_bf = qkv_bf + qkv_elems;             // 768*256 bf16
    unsigned short* W2 = wqkv_bf + 768 * 256;                 // 2*256*256 bf16
    float* num  = (float*)(W2 + 2 * 256 * 256);               // 16384
    float* den  = num + 16384;                                // 512

    hipMemsetAsync(num, 0, (16384 + 512) * sizeof(float), stream);

    // 0) cast w_qkv to bf16
    cast_bf16_kernel<<<192, 256, 0, stream>>>(w_qkv, wqkv_bf, 768 * 256 / 4);

    // 1) qkv = w_qkv @ x, q rows softmax'd in-epilogue; B (x) read once
    gemm_bstat<float, unsigned short, 6, true><<<dim3(256, 2), 256, 0, stream>>>(
        wqkv_bf, x, qkv_bf, 0L, 256L * NTOK, 768L * NTOK);

    // 2) context num/den
    ctx_kernel<<<dim3(32, 8, 2), 256, 0, stream>>>(qkv_bf, num, den, NTOK / 32);

    // 3) W2 = fold(w_out, context) -> bf16
    combine_kernel<<<512, 256, 0, stream>>>(w_out, num, den, W2);

    // 4) out(fp32) = W2(bf16) @ q_soft(bf16); B (q_soft) read once
    gemm_bstat<unsigned short, float, 2, false><<<dim3(256, 2), 256, 0, stream>>>(
        W2, qkv_bf, out, 65536L, 768L * NTOK, 256L * NTOK);
}